// Round 17
// baseline (398.525 us; speedup 1.0000x reference)
//
#include <hip/hip_runtime.h>
#include <cstdint>
#include <cstddef>

static const int NN = 100000;
static const int NE = 1600000;
static const int F  = 128;       // K dim (feature width)
static const int BKT_SHIFT = 7;  // 128 nodes per bucket
static const int BNODES = 1 << BKT_SHIFT;
static const int NBKT = (NN + BNODES - 1) >> BKT_SHIFT;   // 782
static const int PKCAP = 4096;   // per-bucket region cap (mean 2048, +45 sigma)
static const int SRC_BITS = 17;  // 100000 < 2^17
static const unsigned SRC_MASK = (1u << SRC_BITS) - 1u;

static const int GM = (NN + 127)/128;             // 782 row-tiles
static const int PREPW_B = 320;                   // 81920/256

typedef __attribute__((ext_vector_type(8))) short short8;
typedef __attribute__((ext_vector_type(4))) float float4v;
typedef __attribute__((ext_vector_type(2))) float f32x2;

static __device__ __forceinline__ unsigned f2bf(float f){
    unsigned u = __builtin_bit_cast(unsigned, f);
    return (u + 0x7FFFu + ((u >> 16) & 1u)) >> 16;
}
static __device__ __forceinline__ float bf_lo(unsigned u){
    return __builtin_bit_cast(float, u << 16);
}
static __device__ __forceinline__ float bf_hi(unsigned u){
    return __builtin_bit_cast(float, u & 0xFFFF0000u);
}

// ---------------- K1: bscatter || prepw (grid-partitioned) ----------------

__global__ __launch_bounds__(256) void prep_fused_k(
        const int* __restrict__ src, const int* __restrict__ dst,
        int* __restrict__ bfill, unsigned* __restrict__ pk,
        const float* __restrict__ Ws0, const float* __restrict__ Wn0,
        const float* __restrict__ Ws1, const float* __restrict__ Wn1,
        const float* __restrict__ Ws2, const float* __restrict__ Wn2,
        unsigned short* __restrict__ Wt0, unsigned short* __restrict__ Wt1,
        unsigned short* __restrict__ Wt2){
    __shared__ int sh[2*NBKT];            // hist | gbase (bscatter role only)
    const int bid = blockIdx.x;
    const int t = threadIdx.x;
    if (bid < NBKT){                      // ---- bscatter role ----
        int* hist  = sh;
        int* gbase = sh + NBKT;
        for (int i = t; i < NBKT; i += 256) hist[i] = 0;
        __syncthreads();
        const int e0 = bid * 2048;
        int s[8], d[8], b[8], r[8];
        #pragma unroll
        for (int j = 0; j < 8; ++j){
            int e = e0 + j*256 + t;
            if (e < NE){
                s[j] = src[e]; d[j] = dst[e];
                b[j] = d[j] >> BKT_SHIFT;
                r[j] = atomicAdd(&hist[b[j]], 1);
            }
        }
        __syncthreads();
        for (int i = t; i < NBKT; i += 256){
            int h = hist[i];
            int base = 0;
            if (h) base = atomicAdd(&bfill[i], h);
            gbase[i] = i*PKCAP + base;
        }
        __syncthreads();
        #pragma unroll
        for (int j = 0; j < 8; ++j){
            int e = e0 + j*256 + t;
            if (e < NE)
                pk[gbase[b[j]] + r[j]] =
                    (unsigned)s[j] | ((unsigned)(d[j] & (BNODES-1)) << SRC_BITS);
        }
    } else {                              // ---- prepw role ----
        int i = (bid - NBKT)*256 + t;     // i < 81920
        const float* Ws; const float* Wn; unsigned short* Wt; int D; int idx;
        if (i < 32768){       Ws=Ws0; Wn=Wn0; Wt=Wt0; D=128; idx=i; }
        else if (i < 65536){  Ws=Ws1; Wn=Wn1; Wt=Wt1; D=128; idx=i-32768; }
        else {                Ws=Ws2; Wn=Wn2; Wt=Wt2; D=47;  idx=i-65536; }
        int n = idx >> 7, k = idx & 127;
        float v = 0.f;
        if (n < D)        v = Ws[k*D + n];
        else if (n < 2*D) v = Wn[k*D + (n - D)];
        Wt[n*128 + k] = (unsigned short)f2bf(v);
    }
}

// ---------------- gemm core + staging variants ----------------
// Wave tile is always 64x64 (acc[4][4], bfrag[4][4]); WN selects wave-tile grid.
// LDS layout: slot (row,c) holds global chunk c^(row&7) (swizzled-source staging).

template<int WN>
static __device__ __forceinline__ void gemm_core(char* ldsA,
        const unsigned short* __restrict__ Wt, const float* __restrict__ bias,
        unsigned short* __restrict__ Y, unsigned short* __restrict__ Z,
        int M, int D, int Dpad, int tile, int cbase){
    const int t = threadIdx.x;
    const int lane = t & 63;
    const int w = t >> 6;
    const int wm = w / WN, wn = w % WN;

    short8 bfrag[4][4];
    {
        int ncol = cbase + wn*64;
        #pragma unroll
        for (int n = 0; n < 4; ++n){
            int wrow = ncol + n*16 + (lane & 15);
            const unsigned short* bp = Wt + (size_t)wrow*128 + ((lane >> 4) * 8);
            #pragma unroll
            for (int kk = 0; kk < 4; ++kk)
                bfrag[n][kk] = *(const short8*)(bp + kk*32);
        }
    }

    float4v acc[4][4];
    #pragma unroll
    for (int m = 0; m < 4; ++m)
        #pragma unroll
        for (int n = 0; n < 4; ++n)
            acc[m][n] = (float4v){0.f,0.f,0.f,0.f};

    __syncthreads();

    #pragma unroll
    for (int m = 0; m < 4; ++m){
        int r = wm*64 + m*16 + (lane & 15);
        #pragma unroll
        for (int kk = 0; kk < 4; ++kk){
            int c = kk*4 + (lane >> 4);
            short8 a = *(const short8*)(ldsA + (size_t)r*256 + ((size_t)(c ^ (r & 7)) << 4));
            #pragma unroll
            for (int n = 0; n < 4; ++n)
                acc[m][n] = __builtin_amdgcn_mfma_f32_16x16x32_bf16(a, bfrag[n][kk], acc[m][n], 0, 0, 0);
        }
    }

    #pragma unroll
    for (int m = 0; m < 4; ++m){
        #pragma unroll
        for (int n = 0; n < 4; ++n){
            int c = cbase + wn*64 + n*16 + (lane & 15);
            #pragma unroll
            for (int j = 0; j < 4; ++j){
                int r = tile + wm*64 + m*16 + (lane >> 4)*4 + j;
                if (r < M){
                    float v = acc[m][n][j];
                    if (c < D){
                        v += bias[c];
                        Y[(size_t)r*Dpad + c] = (unsigned short)f2bf(v);
                    } else if (c < 2*D){
                        Z[(size_t)r*Dpad + (c - D)] = (unsigned short)f2bf(v);
                    }
                }
            }
        }
    }
}

// bf16 A staged via async global_load_lds with XOR-pre-swizzled source
template<int WAVES, int WN>
static __device__ __forceinline__ void gemm_body(char* ldsA,
        const unsigned short* __restrict__ hb, const unsigned short* __restrict__ Wt,
        const float* __restrict__ bias,
        unsigned short* __restrict__ Y, unsigned short* __restrict__ Z,
        int M, int D, int Dpad, int tile, int cbase){
    const int t = threadIdx.x;
    const int lane = t & 63;
    const int w = t >> 6;
    #pragma unroll
    for (int i = 0; i < 32/WAVES; ++i){
        int chunkid = i*WAVES + w;
        int lin = chunkid*64 + lane;
        int row = lin >> 4;
        int cs  = lin & 15;
        int grow = tile + row; if (grow >= M) grow = M - 1;
        const char* src = (const char*)hb + (size_t)grow*256 + ((size_t)(cs ^ (row & 7)) << 4);
        __builtin_amdgcn_global_load_lds(
            (const __attribute__((address_space(1))) void*)src,
            (__attribute__((address_space(3))) void*)(ldsA + (size_t)chunkid*1024 + (size_t)lane*16),
            16, 0, 0);
    }
    gemm_core<WN>(ldsA, Wt, bias, Y, Z, M, D, Dpad, tile, cbase);
}

// ---------------- K2: sort || gemm0 (512 threads; A read directly from f32 x) ----------------

__global__ __launch_bounds__(512) void sort_gemm_k(
        const unsigned* __restrict__ pk, const int* __restrict__ bfill,
        int* __restrict__ row_ptr, int* __restrict__ ssorted,
        const float* __restrict__ x, const unsigned short* __restrict__ Wt,
        const float* __restrict__ bias,
        unsigned short* __restrict__ Y, unsigned short* __restrict__ Z, int N){
    __shared__ char smem[128*256];
    const int bid = blockIdx.x;
    const int t = threadIdx.x;
    if (bid < NBKT){                      // ---- sort role ----
        int* hc  = (int*)smem;            // [128]
        int* of  = hc + 128;              // [128]
        int* fi  = of + 128;              // [128]
        int* red = fi + 128;              // [512]
        const int b = bid;
        int part = 0;
        for (int i = t; i < b; i += 512) part += bfill[i];
        red[t] = part;
        if (t < 128){ hc[t] = 0; fi[t] = 0; }
        __syncthreads();
        for (int off = 256; off > 0; off >>= 1){
            if (t < off) red[t] += red[t+off];
            __syncthreads();
        }
        const int rbeg = red[0];
        const int cntb = bfill[b];
        const unsigned* mypk = pk + (size_t)b * PKCAP;
        for (int i = t; i < cntb; i += 512)
            atomicAdd(&hc[mypk[i] >> SRC_BITS], 1);
        __syncthreads();
        if (t < 128) of[t] = hc[t];
        __syncthreads();
        for (int off = 1; off < 128; off <<= 1){
            int add = (t < 128 && t >= off) ? of[t-off] : 0;
            __syncthreads();
            if (t < 128) of[t] += add;
            __syncthreads();
        }
        if (t < 128){
            int excl = of[t] - hc[t];
            of[t] = excl;
            int node = (b << BKT_SHIFT) + t;
            if (node < N) row_ptr[node] = rbeg + excl;
        }
        if (b == 0 && t == 0) row_ptr[N] = NE;
        __syncthreads();
        for (int i = t; i < cntb; i += 512){
            unsigned p = mypk[i];
            int dl = (int)(p >> SRC_BITS);
            int pos = rbeg + of[dl] + atomicAdd(&fi[dl], 1);
            ssorted[pos] = (int)(p & SRC_MASK);
        }
    } else {                              // ---- gemm0 role: A from f32 x, reg-staged ----
        const int tile = (bid - NBKT) * 128;
        // pre-swizzled SOURCE chunk (cs^(row&7)), LINEAR LDS write (lin*16)
        #pragma unroll
        for (int it = 0; it < 4; ++it){
            int lin = it*512 + t;
            int row = lin >> 4;
            int cs  = lin & 15;
            int grow = tile + row; if (grow >= N) grow = N - 1;
            int csg = cs ^ (row & 7);
            const float4* sp = (const float4*)((const char*)x + (size_t)grow*512 + (size_t)csg*32);
            float4 v0 = sp[0], v1 = sp[1];
            uint4 o;
            o.x = f2bf(v0.x) | (f2bf(v0.y) << 16);
            o.y = f2bf(v0.z) | (f2bf(v0.w) << 16);
            o.z = f2bf(v1.x) | (f2bf(v1.y) << 16);
            o.w = f2bf(v1.z) | (f2bf(v1.w) << 16);
            *(uint4*)(smem + (size_t)lin*16) = o;
        }
        gemm_core<4>(smem, Wt, bias, Y, Z, N, 128, 128, tile, 0);
    }
}

// standalone gemms (bf16 A, async staging)
__global__ __launch_bounds__(512) void gemm512_k(
        const unsigned short* __restrict__ hb, const unsigned short* __restrict__ Wt,
        const float* __restrict__ bias,
        unsigned short* __restrict__ Y, unsigned short* __restrict__ Z,
        int M, int D, int Dpad){
    __shared__ char ldsA[128*256];
    gemm_body<8,4>(ldsA, hb, Wt, bias, Y, Z, M, D, Dpad, blockIdx.x*128, 0);
}

__global__ __launch_bounds__(256) void gemm256_k(
        const unsigned short* __restrict__ hb, const unsigned short* __restrict__ Wt,
        const float* __restrict__ bias,
        unsigned short* __restrict__ Y, unsigned short* __restrict__ Z,
        int M, int D, int Dpad){
    __shared__ char ldsA[128*256];
    gemm_body<4,2>(ldsA, hb, Wt, bias, Y, Z, M, D, Dpad, blockIdx.x*128, 0);
}

// ---------------- aggregation ----------------
// out = relu(Y + mean(Z[src])), XCD feat-half sharded: 2x blocks; bid%8 -> XCD
// (round-robin heuristic); XCDs 0-3 process feat-half 0, XCDs 4-7 half 1, so each
// 128B Z half-row is fetched into ~4 L2s instead of ~7 (fetch 181->~101 MB).
// Wave/node; eighth-wave (8 lanes) per edge, uint4/lane, 64 edges in flight
// (8 gathers/lane = 128B/lane MLP). Clamped dup loads are L1 hits. Correct under
// ANY block->XCD mapping (pure permutation of work).

__global__ __launch_bounds__(256) void agg128_k(
        const unsigned short* __restrict__ Yb, const unsigned short* __restrict__ Zb,
        const int* __restrict__ row_ptr, const int* __restrict__ ssorted,
        unsigned short* __restrict__ hout, int N){
    const int lane = threadIdx.x & 63;
    const int slot = lane >> 3;          // edge slot 0..7
    const int sub  = lane & 7;           // 16B feat group within 128B half
    const int bid  = blockIdx.x;
    const int xcd  = bid & 7;
    const int half = xcd >> 2;           // feat-half
    const int ng   = (bid >> 3)*4 + (xcd & 3);
    const int node = ng*4 + (threadIdx.x >> 6);
    if (node >= N) return;
    const int beg = __builtin_amdgcn_readfirstlane(row_ptr[node]);
    const int end = __builtin_amdgcn_readfirstlane(row_ptr[node+1]);
    const float inv = 1.0f / fmaxf((float)(end - beg), 1.0f);
    const char* zc = (const char*)Zb;
    const unsigned boff = (unsigned)(half*128 + sub*16);
    f32x2 a0={0.f,0.f}, a1={0.f,0.f}, a2={0.f,0.f}, a3={0.f,0.f};
    for (int e = beg; e < end; e += 64){
        int s[8];
        #pragma unroll
        for (int j = 0; j < 8; ++j){
            int ei = e + 8*j + slot;
            int ec = ei < end ? ei : end - 1;
            s[j] = ssorted[ec];
        }
        uint4 u[8];
        #pragma unroll
        for (int j = 0; j < 8; ++j)
            u[j] = *(const uint4*)(zc + ((unsigned)s[j]*256u + boff));
        #pragma unroll
        for (int j = 0; j < 8; ++j){
            if (e + 8*j + slot < end){
                a0 += (f32x2){ bf_lo(u[j].x), bf_hi(u[j].x) };
                a1 += (f32x2){ bf_lo(u[j].y), bf_hi(u[j].y) };
                a2 += (f32x2){ bf_lo(u[j].z), bf_hi(u[j].z) };
                a3 += (f32x2){ bf_lo(u[j].w), bf_hi(u[j].w) };
            }
        }
    }
    // reduce across the 8 edge slots (lane bits 3,4,5)
    a0.x += __shfl_xor(a0.x,8,64); a0.x += __shfl_xor(a0.x,16,64); a0.x += __shfl_xor(a0.x,32,64);
    a0.y += __shfl_xor(a0.y,8,64); a0.y += __shfl_xor(a0.y,16,64); a0.y += __shfl_xor(a0.y,32,64);
    a1.x += __shfl_xor(a1.x,8,64); a1.x += __shfl_xor(a1.x,16,64); a1.x += __shfl_xor(a1.x,32,64);
    a1.y += __shfl_xor(a1.y,8,64); a1.y += __shfl_xor(a1.y,16,64); a1.y += __shfl_xor(a1.y,32,64);
    a2.x += __shfl_xor(a2.x,8,64); a2.x += __shfl_xor(a2.x,16,64); a2.x += __shfl_xor(a2.x,32,64);
    a2.y += __shfl_xor(a2.y,8,64); a2.y += __shfl_xor(a2.y,16,64); a2.y += __shfl_xor(a2.y,32,64);
    a3.x += __shfl_xor(a3.x,8,64); a3.x += __shfl_xor(a3.x,16,64); a3.x += __shfl_xor(a3.x,32,64);
    a3.y += __shfl_xor(a3.y,8,64); a3.y += __shfl_xor(a3.y,16,64); a3.y += __shfl_xor(a3.y,32,64);
    if (slot == 0){
        uint4 yu = *(const uint4*)((const char*)Yb + (size_t)node*256 + boff);
        float r0 = fmaxf(bf_lo(yu.x) + a0.x*inv, 0.f);
        float r1 = fmaxf(bf_hi(yu.x) + a0.y*inv, 0.f);
        float r2 = fmaxf(bf_lo(yu.y) + a1.x*inv, 0.f);
        float r3 = fmaxf(bf_hi(yu.y) + a1.y*inv, 0.f);
        float r4 = fmaxf(bf_lo(yu.z) + a2.x*inv, 0.f);
        float r5 = fmaxf(bf_hi(yu.z) + a2.y*inv, 0.f);
        float r6 = fmaxf(bf_lo(yu.w) + a3.x*inv, 0.f);
        float r7 = fmaxf(bf_hi(yu.w) + a3.y*inv, 0.f);
        uint4 o;
        o.x = f2bf(r0) | (f2bf(r1) << 16);
        o.y = f2bf(r2) | (f2bf(r3) << 16);
        o.z = f2bf(r4) | (f2bf(r5) << 16);
        o.w = f2bf(r6) | (f2bf(r7) << 16);
        *(uint4*)((char*)hout + (size_t)node*256 + boff) = o;
    }
}

// final layer: D=47, Dpad=64 (128 B rows). Eighth-wave per edge, uint4/lane,
// all 64 lanes active. Cols 47-63 = finite stale bf16, accumulated, never written.
__global__ __launch_bounds__(256) void aggfin_k(
        const unsigned short* __restrict__ Yb, const unsigned short* __restrict__ Zb,
        const int* __restrict__ row_ptr, const int* __restrict__ ssorted,
        float* __restrict__ out, int N){
    const int lane = threadIdx.x & 63;
    const int slot = lane >> 3;
    const int sub  = lane & 7;
    const int node = blockIdx.x*4 + (threadIdx.x >> 6);
    if (node >= N) return;
    const int beg = __builtin_amdgcn_readfirstlane(row_ptr[node]);
    const int end = __builtin_amdgcn_readfirstlane(row_ptr[node+1]);
    const float inv = 1.0f / fmaxf((float)(end - beg), 1.0f);
    const char* zc = (const char*)Zb;
    const unsigned boff = (unsigned)(sub*16);
    f32x2 a0={0.f,0.f}, a1={0.f,0.f}, a2={0.f,0.f}, a3={0.f,0.f};
    for (int e = beg; e < end; e += 32){
        int s[4];
        #pragma unroll
        for (int j = 0; j < 4; ++j){
            int ei = e + 8*j + slot;
            int ec = ei < end ? ei : end - 1;
            s[j] = ssorted[ec];
        }
        uint4 u[4];
        #pragma unroll
        for (int j = 0; j < 4; ++j)
            u[j] = *(const uint4*)(zc + ((unsigned)s[j]*128u + boff));
        #pragma unroll
        for (int j = 0; j < 4; ++j){
            if (e + 8*j + slot < end){
                a0 += (f32x2){ bf_lo(u[j].x), bf_hi(u[j].x) };
                a1 += (f32x2){ bf_lo(u[j].y), bf_hi(u[j].y) };
                a2 += (f32x2){ bf_lo(u[j].z), bf_hi(u[j].z) };
                a3 += (f32x2){ bf_lo(u[j].w), bf_hi(u[j].w) };
            }
        }
    }
    a0.x += __shfl_xor(a0.x,8,64); a0.x += __shfl_xor(a0.x,16,64); a0.x += __shfl_xor(a0.x,32,64);
    a0.y += __shfl_xor(a0.y,8,64); a0.y += __shfl_xor(a0.y,16,64); a0.y += __shfl_xor(a0.y,32,64);
    a1.x += __shfl_xor(a1.x,8,64); a1.x += __shfl_xor(a1.x,16,64); a1.x += __shfl_xor(a1.x,32,64);
    a1.y += __shfl_xor(a1.y,8,64); a1.y += __shfl_xor(a1.y,16,64); a1.y += __shfl_xor(a1.y,32,64);
    a2.x += __shfl_xor(a2.x,8,64); a2.x += __shfl_xor(a2.x,16,64); a2.x += __shfl_xor(a2.x,32,64);
    a2.y += __shfl_xor(a2.y,8,64); a2.y += __shfl_xor(a2.y,16,64); a2.y += __shfl_xor(a2.y,32,64);
    a3.x += __shfl_xor(a3.x,8,64); a3.x += __shfl_xor(a3.x,16,64); a3.x += __shfl_xor(a3.x,32,64);
    a3.y += __shfl_xor(a3.y,8,64); a3.y += __shfl_xor(a3.y,16,64); a3.y += __shfl_xor(a3.y,32,64);
    if (slot == 0){
        uint4 yu = *(const uint4*)((const char*)Yb + (size_t)node*128 + sub*16);
        float v[8];
        v[0] = bf_lo(yu.x) + a0.x*inv;
        v[1] = bf_hi(yu.x) + a0.y*inv;
        v[2] = bf_lo(yu.y) + a1.x*inv;
        v[3] = bf_hi(yu.y) + a1.y*inv;
        v[4] = bf_lo(yu.z) + a2.x*inv;
        v[5] = bf_hi(yu.z) + a2.y*inv;
        v[6] = bf_lo(yu.w) + a3.x*inv;
        v[7] = bf_hi(yu.w) + a3.y*inv;
        int f = sub*8;
        size_t o = (size_t)node*47 + f;
        #pragma unroll
        for (int k = 0; k < 8; ++k)
            if (f + k < 47) out[o + k] = v[k];
    }
}

// ---------------- launch ----------------

extern "C" void kernel_launch(void* const* d_in, const int* in_sizes, int n_in,
                              void* d_out, int out_size, void* d_ws, size_t ws_size,
                              hipStream_t stream){
    const float* x   = (const float*)d_in[0];
    const int*   src = (const int*)  d_in[1];
    const int*   dstv= (const int*)  d_in[2];
    const float* Ws0 = (const float*)d_in[3];
    const float* Wn0 = (const float*)d_in[4];
    const float* b0  = (const float*)d_in[5];
    const float* Ws1 = (const float*)d_in[6];
    const float* Wn1 = (const float*)d_in[7];
    const float* b1  = (const float*)d_in[8];
    const float* Ws2 = (const float*)d_in[9];
    const float* Wn2 = (const float*)d_in[10];
    const float* b2  = (const float*)d_in[11];
    float* out = (float*)d_out;
    const int N = NN;

    char* w = (char*)d_ws;
    size_t off = 0;
    auto alloc = [&](size_t bytes)->char*{
        char* p = w + off; off += (bytes + 255) & ~(size_t)255; return p;
    };
    int*   bfill   = (int*)  alloc((size_t)NBKT*4);
    int*   row_ptr = (int*)  alloc((size_t)(NN+1)*4);
    int*   ssorted = (int*)  alloc((size_t)NE*4);
    unsigned* pk   = (unsigned*)alloc((size_t)NBKT*PKCAP*4);
    unsigned short* hA  = (unsigned short*)alloc((size_t)NN*F*2);
    unsigned short* hB  = (unsigned short*)alloc((size_t)NN*F*2);
    unsigned short* Yb  = (unsigned short*)alloc((size_t)NN*F*2);
    unsigned short* Zb  = (unsigned short*)alloc((size_t)NN*F*2);
    unsigned short* Wt0 = (unsigned short*)alloc((size_t)256*128*2);
    unsigned short* Wt1 = (unsigned short*)alloc((size_t)256*128*2);
    unsigned short* Wt2 = (unsigned short*)alloc((size_t)128*128*2);
    (void)ws_size; (void)n_in; (void)in_sizes; (void)out_size;

    hipMemsetAsync(bfill, 0, (size_t)NBKT*4, stream);

    // K1: bscatter || prepw
    prep_fused_k<<<NBKT + PREPW_B, 256, 0, stream>>>(
        src, dstv, bfill, pk,
        Ws0, Wn0, Ws1, Wn1, Ws2, Wn2, Wt0, Wt1, Wt2);

    // K2: sort || gemm layer 0 (A read directly from f32 x, converted in staging)
    sort_gemm_k<<<NBKT + GM, 512, 0, stream>>>(
        pk, bfill, row_ptr, ssorted, x, Wt0, b0, Yb, Zb, N);

    const int GA  = (N + 3)/4;            // 25000 node-groups
    const int GA2 = GA*2;                 // x2 feat-half sharding

    agg128_k <<<GA2, 256, 0, stream>>>(Yb, Zb, row_ptr, ssorted, hA, N);
    gemm512_k<<<GM, 512, 0, stream>>>(hA, Wt1, b1, Yb, Zb, N, 128, 128);
    agg128_k <<<GA2, 256, 0, stream>>>(Yb, Zb, row_ptr, ssorted, hB, N);
    gemm256_k<<<GM, 256, 0, stream>>>(hB, Wt2, b2, Yb, Zb, N, 47, 64);
    aggfin_k <<<GA, 256, 0, stream>>>(Yb, Zb, row_ptr, ssorted, out, N);
}

// Round 18
// 337.110 us; speedup vs baseline: 1.1822x; 1.1822x over previous
//
#include <hip/hip_runtime.h>
#include <cstdint>
#include <cstddef>

static const int NN = 100000;
static const int NE = 1600000;
static const int F  = 128;       // K dim (feature width)
static const int BKT_SHIFT = 7;  // 128 nodes per bucket
static const int BNODES = 1 << BKT_SHIFT;
static const int NBKT = (NN + BNODES - 1) >> BKT_SHIFT;   // 782
static const int PKCAP = 4096;   // per-bucket region cap (mean 2048, +45 sigma)
static const int SRC_BITS = 17;  // 100000 < 2^17
static const unsigned SRC_MASK = (1u << SRC_BITS) - 1u;

static const int GM = (NN + 127)/128;             // 782 row-tiles
static const int PREPW_B = 320;                   // 81920/256

typedef __attribute__((ext_vector_type(8))) short short8;
typedef __attribute__((ext_vector_type(4))) float float4v;
typedef __attribute__((ext_vector_type(2))) float f32x2;

static __device__ __forceinline__ unsigned f2bf(float f){
    unsigned u = __builtin_bit_cast(unsigned, f);
    return (u + 0x7FFFu + ((u >> 16) & 1u)) >> 16;
}
static __device__ __forceinline__ float bf_lo(unsigned u){
    return __builtin_bit_cast(float, u << 16);
}
static __device__ __forceinline__ float bf_hi(unsigned u){
    return __builtin_bit_cast(float, u & 0xFFFF0000u);
}

// ---------------- K1: bscatter || prepw (grid-partitioned) ----------------

__global__ __launch_bounds__(256) void prep_fused_k(
        const int* __restrict__ src, const int* __restrict__ dst,
        int* __restrict__ bfill, unsigned* __restrict__ pk,
        const float* __restrict__ Ws0, const float* __restrict__ Wn0,
        const float* __restrict__ Ws1, const float* __restrict__ Wn1,
        const float* __restrict__ Ws2, const float* __restrict__ Wn2,
        unsigned short* __restrict__ Wt0, unsigned short* __restrict__ Wt1,
        unsigned short* __restrict__ Wt2){
    __shared__ int sh[2*NBKT];            // hist | gbase (bscatter role only)
    const int bid = blockIdx.x;
    const int t = threadIdx.x;
    if (bid < NBKT){                      // ---- bscatter role ----
        int* hist  = sh;
        int* gbase = sh + NBKT;
        for (int i = t; i < NBKT; i += 256) hist[i] = 0;
        __syncthreads();
        const int e0 = bid * 2048;
        int s[8], d[8], b[8], r[8];
        #pragma unroll
        for (int j = 0; j < 8; ++j){
            int e = e0 + j*256 + t;
            if (e < NE){
                s[j] = src[e]; d[j] = dst[e];
                b[j] = d[j] >> BKT_SHIFT;
                r[j] = atomicAdd(&hist[b[j]], 1);
            }
        }
        __syncthreads();
        for (int i = t; i < NBKT; i += 256){
            int h = hist[i];
            int base = 0;
            if (h) base = atomicAdd(&bfill[i], h);
            gbase[i] = i*PKCAP + base;
        }
        __syncthreads();
        #pragma unroll
        for (int j = 0; j < 8; ++j){
            int e = e0 + j*256 + t;
            if (e < NE)
                pk[gbase[b[j]] + r[j]] =
                    (unsigned)s[j] | ((unsigned)(d[j] & (BNODES-1)) << SRC_BITS);
        }
    } else {                              // ---- prepw role ----
        int i = (bid - NBKT)*256 + t;     // i < 81920
        const float* Ws; const float* Wn; unsigned short* Wt; int D; int idx;
        if (i < 32768){       Ws=Ws0; Wn=Wn0; Wt=Wt0; D=128; idx=i; }
        else if (i < 65536){  Ws=Ws1; Wn=Wn1; Wt=Wt1; D=128; idx=i-32768; }
        else {                Ws=Ws2; Wn=Wn2; Wt=Wt2; D=47;  idx=i-65536; }
        int n = idx >> 7, k = idx & 127;
        float v = 0.f;
        if (n < D)        v = Ws[k*D + n];
        else if (n < 2*D) v = Wn[k*D + (n - D)];
        Wt[n*128 + k] = (unsigned short)f2bf(v);
    }
}

// ---------------- gemm core + staging variants ----------------
// Wave tile is always 64x64 (acc[4][4], bfrag[4][4]); WN selects wave-tile grid.
// LDS layout: slot (row,c) holds global chunk c^(row&7) (swizzled-source staging).

template<int WN>
static __device__ __forceinline__ void gemm_core(char* ldsA,
        const unsigned short* __restrict__ Wt, const float* __restrict__ bias,
        unsigned short* __restrict__ Y, unsigned short* __restrict__ Z,
        int M, int D, int Dpad, int tile, int cbase){
    const int t = threadIdx.x;
    const int lane = t & 63;
    const int w = t >> 6;
    const int wm = w / WN, wn = w % WN;

    short8 bfrag[4][4];
    {
        int ncol = cbase + wn*64;
        #pragma unroll
        for (int n = 0; n < 4; ++n){
            int wrow = ncol + n*16 + (lane & 15);
            const unsigned short* bp = Wt + (size_t)wrow*128 + ((lane >> 4) * 8);
            #pragma unroll
            for (int kk = 0; kk < 4; ++kk)
                bfrag[n][kk] = *(const short8*)(bp + kk*32);
        }
    }

    float4v acc[4][4];
    #pragma unroll
    for (int m = 0; m < 4; ++m)
        #pragma unroll
        for (int n = 0; n < 4; ++n)
            acc[m][n] = (float4v){0.f,0.f,0.f,0.f};

    __syncthreads();

    #pragma unroll
    for (int m = 0; m < 4; ++m){
        int r = wm*64 + m*16 + (lane & 15);
        #pragma unroll
        for (int kk = 0; kk < 4; ++kk){
            int c = kk*4 + (lane >> 4);
            short8 a = *(const short8*)(ldsA + (size_t)r*256 + ((size_t)(c ^ (r & 7)) << 4));
            #pragma unroll
            for (int n = 0; n < 4; ++n)
                acc[m][n] = __builtin_amdgcn_mfma_f32_16x16x32_bf16(a, bfrag[n][kk], acc[m][n], 0, 0, 0);
        }
    }

    #pragma unroll
    for (int m = 0; m < 4; ++m){
        #pragma unroll
        for (int n = 0; n < 4; ++n){
            int c = cbase + wn*64 + n*16 + (lane & 15);
            #pragma unroll
            for (int j = 0; j < 4; ++j){
                int r = tile + wm*64 + m*16 + (lane >> 4)*4 + j;
                if (r < M){
                    float v = acc[m][n][j];
                    if (c < D){
                        v += bias[c];
                        Y[(size_t)r*Dpad + c] = (unsigned short)f2bf(v);
                    } else if (c < 2*D){
                        Z[(size_t)r*Dpad + (c - D)] = (unsigned short)f2bf(v);
                    }
                }
            }
        }
    }
}

// bf16 A staged via async global_load_lds with XOR-pre-swizzled source
template<int WAVES, int WN>
static __device__ __forceinline__ void gemm_body(char* ldsA,
        const unsigned short* __restrict__ hb, const unsigned short* __restrict__ Wt,
        const float* __restrict__ bias,
        unsigned short* __restrict__ Y, unsigned short* __restrict__ Z,
        int M, int D, int Dpad, int tile, int cbase){
    const int t = threadIdx.x;
    const int lane = t & 63;
    const int w = t >> 6;
    #pragma unroll
    for (int i = 0; i < 32/WAVES; ++i){
        int chunkid = i*WAVES + w;
        int lin = chunkid*64 + lane;
        int row = lin >> 4;
        int cs  = lin & 15;
        int grow = tile + row; if (grow >= M) grow = M - 1;
        const char* src = (const char*)hb + (size_t)grow*256 + ((size_t)(cs ^ (row & 7)) << 4);
        __builtin_amdgcn_global_load_lds(
            (const __attribute__((address_space(1))) void*)src,
            (__attribute__((address_space(3))) void*)(ldsA + (size_t)chunkid*1024 + (size_t)lane*16),
            16, 0, 0);
    }
    gemm_core<WN>(ldsA, Wt, bias, Y, Z, M, D, Dpad, tile, cbase);
}

// ---------------- K2: sort || gemm0 (512 threads; A read directly from f32 x) ----------------

__global__ __launch_bounds__(512) void sort_gemm_k(
        const unsigned* __restrict__ pk, const int* __restrict__ bfill,
        int* __restrict__ row_ptr, int* __restrict__ ssorted,
        const float* __restrict__ x, const unsigned short* __restrict__ Wt,
        const float* __restrict__ bias,
        unsigned short* __restrict__ Y, unsigned short* __restrict__ Z, int N){
    __shared__ char smem[128*256];
    const int bid = blockIdx.x;
    const int t = threadIdx.x;
    if (bid < NBKT){                      // ---- sort role ----
        int* hc  = (int*)smem;            // [128]
        int* of  = hc + 128;              // [128]
        int* fi  = of + 128;              // [128]
        int* red = fi + 128;              // [512]
        const int b = bid;
        int part = 0;
        for (int i = t; i < b; i += 512) part += bfill[i];
        red[t] = part;
        if (t < 128){ hc[t] = 0; fi[t] = 0; }
        __syncthreads();
        for (int off = 256; off > 0; off >>= 1){
            if (t < off) red[t] += red[t+off];
            __syncthreads();
        }
        const int rbeg = red[0];
        const int cntb = bfill[b];
        const unsigned* mypk = pk + (size_t)b * PKCAP;
        for (int i = t; i < cntb; i += 512)
            atomicAdd(&hc[mypk[i] >> SRC_BITS], 1);
        __syncthreads();
        if (t < 128) of[t] = hc[t];
        __syncthreads();
        for (int off = 1; off < 128; off <<= 1){
            int add = (t < 128 && t >= off) ? of[t-off] : 0;
            __syncthreads();
            if (t < 128) of[t] += add;
            __syncthreads();
        }
        if (t < 128){
            int excl = of[t] - hc[t];
            of[t] = excl;
            int node = (b << BKT_SHIFT) + t;
            if (node < N) row_ptr[node] = rbeg + excl;
        }
        if (b == 0 && t == 0) row_ptr[N] = NE;
        __syncthreads();
        for (int i = t; i < cntb; i += 512){
            unsigned p = mypk[i];
            int dl = (int)(p >> SRC_BITS);
            int pos = rbeg + of[dl] + atomicAdd(&fi[dl], 1);
            ssorted[pos] = (int)(p & SRC_MASK);
        }
    } else {                              // ---- gemm0 role: A from f32 x, reg-staged ----
        const int tile = (bid - NBKT) * 128;
        // pre-swizzled SOURCE chunk (cs^(row&7)), LINEAR LDS write (lin*16)
        #pragma unroll
        for (int it = 0; it < 4; ++it){
            int lin = it*512 + t;
            int row = lin >> 4;
            int cs  = lin & 15;
            int grow = tile + row; if (grow >= N) grow = N - 1;
            int csg = cs ^ (row & 7);
            const float4* sp = (const float4*)((const char*)x + (size_t)grow*512 + (size_t)csg*32);
            float4 v0 = sp[0], v1 = sp[1];
            uint4 o;
            o.x = f2bf(v0.x) | (f2bf(v0.y) << 16);
            o.y = f2bf(v0.z) | (f2bf(v0.w) << 16);
            o.z = f2bf(v1.x) | (f2bf(v1.y) << 16);
            o.w = f2bf(v1.z) | (f2bf(v1.w) << 16);
            *(uint4*)(smem + (size_t)lin*16) = o;
        }
        gemm_core<4>(smem, Wt, bias, Y, Z, N, 128, 128, tile, 0);
    }
}

// standalone gemms (bf16 A, async staging)
__global__ __launch_bounds__(512) void gemm512_k(
        const unsigned short* __restrict__ hb, const unsigned short* __restrict__ Wt,
        const float* __restrict__ bias,
        unsigned short* __restrict__ Y, unsigned short* __restrict__ Z,
        int M, int D, int Dpad){
    __shared__ char ldsA[128*256];
    gemm_body<8,4>(ldsA, hb, Wt, bias, Y, Z, M, D, Dpad, blockIdx.x*128, 0);
}

__global__ __launch_bounds__(256) void gemm256_k(
        const unsigned short* __restrict__ hb, const unsigned short* __restrict__ Wt,
        const float* __restrict__ bias,
        unsigned short* __restrict__ Y, unsigned short* __restrict__ Z,
        int M, int D, int Dpad){
    __shared__ char ldsA[128*256];
    gemm_body<4,2>(ldsA, hb, Wt, bias, Y, Z, M, D, Dpad, blockIdx.x*128, 0);
}

// ---------------- aggregation ----------------
// out = relu(Y + mean(Z[src])). One wave/node; quarter-wave per edge, uint4/lane,
// 32 edges in flight. Unconditional clamped loads (dups = L1 hits); adds predicated.
// Lean VGPR (28) -> occupancy ~76%. This form is the empirical optimum (rounds
// 8-17): any added per-edge instructions (shfl cache, predicated loads, feat-half
// sharding) regressed via VGPR/occupancy or issue overhead.

__global__ __launch_bounds__(256) void agg128_k(
        const unsigned short* __restrict__ Yb, const unsigned short* __restrict__ Zb,
        const int* __restrict__ row_ptr, const int* __restrict__ ssorted,
        unsigned short* __restrict__ hout, int N){
    const int lane = threadIdx.x & 63;
    const int q   = lane >> 4;
    const int sub = lane & 15;
    const int node = blockIdx.x*4 + (threadIdx.x >> 6);
    if (node >= N) return;
    const int beg = __builtin_amdgcn_readfirstlane(row_ptr[node]);
    const int end = __builtin_amdgcn_readfirstlane(row_ptr[node+1]);
    const float inv = 1.0f / fmaxf((float)(end - beg), 1.0f);
    const char* zc = (const char*)Zb;
    const unsigned boff = (unsigned)(sub*16);
    f32x2 a0={0.f,0.f}, a1={0.f,0.f}, a2={0.f,0.f}, a3={0.f,0.f};
    for (int e = beg; e < end; e += 32){
        int s[8];
        #pragma unroll
        for (int j = 0; j < 8; ++j){
            int ei = e + 4*j + q;
            int ec = ei < end ? ei : end - 1;
            s[j] = ssorted[ec];
        }
        uint4 u[8];
        #pragma unroll
        for (int j = 0; j < 8; ++j)
            u[j] = *(const uint4*)(zc + ((unsigned)s[j]*256u + boff));
        #pragma unroll
        for (int j = 0; j < 8; ++j){
            if (e + 4*j + q < end){
                a0 += (f32x2){ bf_lo(u[j].x), bf_hi(u[j].x) };
                a1 += (f32x2){ bf_lo(u[j].y), bf_hi(u[j].y) };
                a2 += (f32x2){ bf_lo(u[j].z), bf_hi(u[j].z) };
                a3 += (f32x2){ bf_lo(u[j].w), bf_hi(u[j].w) };
            }
        }
    }
    a0.x += __shfl_xor(a0.x,16,64); a0.x += __shfl_xor(a0.x,32,64);
    a0.y += __shfl_xor(a0.y,16,64); a0.y += __shfl_xor(a0.y,32,64);
    a1.x += __shfl_xor(a1.x,16,64); a1.x += __shfl_xor(a1.x,32,64);
    a1.y += __shfl_xor(a1.y,16,64); a1.y += __shfl_xor(a1.y,32,64);
    a2.x += __shfl_xor(a2.x,16,64); a2.x += __shfl_xor(a2.x,32,64);
    a2.y += __shfl_xor(a2.y,16,64); a2.y += __shfl_xor(a2.y,32,64);
    a3.x += __shfl_xor(a3.x,16,64); a3.x += __shfl_xor(a3.x,32,64);
    a3.y += __shfl_xor(a3.y,16,64); a3.y += __shfl_xor(a3.y,32,64);
    if (q == 0){
        uint4 yu = *(const uint4*)((const char*)Yb + (size_t)node*256 + sub*16);
        float r0 = fmaxf(bf_lo(yu.x) + a0.x*inv, 0.f);
        float r1 = fmaxf(bf_hi(yu.x) + a0.y*inv, 0.f);
        float r2 = fmaxf(bf_lo(yu.y) + a1.x*inv, 0.f);
        float r3 = fmaxf(bf_hi(yu.y) + a1.y*inv, 0.f);
        float r4 = fmaxf(bf_lo(yu.z) + a2.x*inv, 0.f);
        float r5 = fmaxf(bf_hi(yu.z) + a2.y*inv, 0.f);
        float r6 = fmaxf(bf_lo(yu.w) + a3.x*inv, 0.f);
        float r7 = fmaxf(bf_hi(yu.w) + a3.y*inv, 0.f);
        uint4 o;
        o.x = f2bf(r0) | (f2bf(r1) << 16);
        o.y = f2bf(r2) | (f2bf(r3) << 16);
        o.z = f2bf(r4) | (f2bf(r5) << 16);
        o.w = f2bf(r6) | (f2bf(r7) << 16);
        *(uint4*)((char*)hout + (size_t)node*256 + sub*16) = o;
    }
}

// final layer: D=47, Dpad=64 (128 B rows). Eighth-wave per edge, uint4/lane,
// all 64 lanes active. Cols 47-63 = finite stale bf16, accumulated, never written.
__global__ __launch_bounds__(256) void aggfin_k(
        const unsigned short* __restrict__ Yb, const unsigned short* __restrict__ Zb,
        const int* __restrict__ row_ptr, const int* __restrict__ ssorted,
        float* __restrict__ out, int N){
    const int lane = threadIdx.x & 63;
    const int slot = lane >> 3;
    const int sub  = lane & 7;
    const int node = blockIdx.x*4 + (threadIdx.x >> 6);
    if (node >= N) return;
    const int beg = __builtin_amdgcn_readfirstlane(row_ptr[node]);
    const int end = __builtin_amdgcn_readfirstlane(row_ptr[node+1]);
    const float inv = 1.0f / fmaxf((float)(end - beg), 1.0f);
    const char* zc = (const char*)Zb;
    const unsigned boff = (unsigned)(sub*16);
    f32x2 a0={0.f,0.f}, a1={0.f,0.f}, a2={0.f,0.f}, a3={0.f,0.f};
    for (int e = beg; e < end; e += 32){
        int s[4];
        #pragma unroll
        for (int j = 0; j < 4; ++j){
            int ei = e + 8*j + slot;
            int ec = ei < end ? ei : end - 1;
            s[j] = ssorted[ec];
        }
        uint4 u[4];
        #pragma unroll
        for (int j = 0; j < 4; ++j)
            u[j] = *(const uint4*)(zc + ((unsigned)s[j]*128u + boff));
        #pragma unroll
        for (int j = 0; j < 4; ++j){
            if (e + 8*j + slot < end){
                a0 += (f32x2){ bf_lo(u[j].x), bf_hi(u[j].x) };
                a1 += (f32x2){ bf_lo(u[j].y), bf_hi(u[j].y) };
                a2 += (f32x2){ bf_lo(u[j].z), bf_hi(u[j].z) };
                a3 += (f32x2){ bf_lo(u[j].w), bf_hi(u[j].w) };
            }
        }
    }
    a0.x += __shfl_xor(a0.x,8,64); a0.x += __shfl_xor(a0.x,16,64); a0.x += __shfl_xor(a0.x,32,64);
    a0.y += __shfl_xor(a0.y,8,64); a0.y += __shfl_xor(a0.y,16,64); a0.y += __shfl_xor(a0.y,32,64);
    a1.x += __shfl_xor(a1.x,8,64); a1.x += __shfl_xor(a1.x,16,64); a1.x += __shfl_xor(a1.x,32,64);
    a1.y += __shfl_xor(a1.y,8,64); a1.y += __shfl_xor(a1.y,16,64); a1.y += __shfl_xor(a1.y,32,64);
    a2.x += __shfl_xor(a2.x,8,64); a2.x += __shfl_xor(a2.x,16,64); a2.x += __shfl_xor(a2.x,32,64);
    a2.y += __shfl_xor(a2.y,8,64); a2.y += __shfl_xor(a2.y,16,64); a2.y += __shfl_xor(a2.y,32,64);
    a3.x += __shfl_xor(a3.x,8,64); a3.x += __shfl_xor(a3.x,16,64); a3.x += __shfl_xor(a3.x,32,64);
    a3.y += __shfl_xor(a3.y,8,64); a3.y += __shfl_xor(a3.y,16,64); a3.y += __shfl_xor(a3.y,32,64);
    if (slot == 0){
        uint4 yu = *(const uint4*)((const char*)Yb + (size_t)node*128 + sub*16);
        float v[8];
        v[0] = bf_lo(yu.x) + a0.x*inv;
        v[1] = bf_hi(yu.x) + a0.y*inv;
        v[2] = bf_lo(yu.y) + a1.x*inv;
        v[3] = bf_hi(yu.y) + a1.y*inv;
        v[4] = bf_lo(yu.z) + a2.x*inv;
        v[5] = bf_hi(yu.z) + a2.y*inv;
        v[6] = bf_lo(yu.w) + a3.x*inv;
        v[7] = bf_hi(yu.w) + a3.y*inv;
        int f = sub*8;
        size_t o = (size_t)node*47 + f;
        #pragma unroll
        for (int k = 0; k < 8; ++k)
            if (f + k < 47) out[o + k] = v[k];
    }
}

// ---------------- launch ----------------

extern "C" void kernel_launch(void* const* d_in, const int* in_sizes, int n_in,
                              void* d_out, int out_size, void* d_ws, size_t ws_size,
                              hipStream_t stream){
    const float* x   = (const float*)d_in[0];
    const int*   src = (const int*)  d_in[1];
    const int*   dstv= (const int*)  d_in[2];
    const float* Ws0 = (const float*)d_in[3];
    const float* Wn0 = (const float*)d_in[4];
    const float* b0  = (const float*)d_in[5];
    const float* Ws1 = (const float*)d_in[6];
    const float* Wn1 = (const float*)d_in[7];
    const float* b1  = (const float*)d_in[8];
    const float* Ws2 = (const float*)d_in[9];
    const float* Wn2 = (const float*)d_in[10];
    const float* b2  = (const float*)d_in[11];
    float* out = (float*)d_out;
    const int N = NN;

    char* w = (char*)d_ws;
    size_t off = 0;
    auto alloc = [&](size_t bytes)->char*{
        char* p = w + off; off += (bytes + 255) & ~(size_t)255; return p;
    };
    int*   bfill   = (int*)  alloc((size_t)NBKT*4);
    int*   row_ptr = (int*)  alloc((size_t)(NN+1)*4);
    int*   ssorted = (int*)  alloc((size_t)NE*4);
    unsigned* pk   = (unsigned*)alloc((size_t)NBKT*PKCAP*4);
    unsigned short* hA  = (unsigned short*)alloc((size_t)NN*F*2);
    unsigned short* hB  = (unsigned short*)alloc((size_t)NN*F*2);
    unsigned short* Yb  = (unsigned short*)alloc((size_t)NN*F*2);
    unsigned short* Zb  = (unsigned short*)alloc((size_t)NN*F*2);
    unsigned short* Wt0 = (unsigned short*)alloc((size_t)256*128*2);
    unsigned short* Wt1 = (unsigned short*)alloc((size_t)256*128*2);
    unsigned short* Wt2 = (unsigned short*)alloc((size_t)128*128*2);
    (void)ws_size; (void)n_in; (void)in_sizes; (void)out_size;

    hipMemsetAsync(bfill, 0, (size_t)NBKT*4, stream);

    // K1: bscatter || prepw
    prep_fused_k<<<NBKT + PREPW_B, 256, 0, stream>>>(
        src, dstv, bfill, pk,
        Ws0, Wn0, Ws1, Wn1, Ws2, Wn2, Wt0, Wt1, Wt2);

    // K2: sort || gemm layer 0 (A read directly from f32 x, converted in staging)
    sort_gemm_k<<<NBKT + GM, 512, 0, stream>>>(
        pk, bfill, row_ptr, ssorted, x, Wt0, b0, Yb, Zb, N);

    const int GA = (N + 3)/4;

    agg128_k <<<GA, 256, 0, stream>>>(Yb, Zb, row_ptr, ssorted, hA, N);
    gemm512_k<<<GM, 512, 0, stream>>>(hA, Wt1, b1, Yb, Zb, N, 128, 128);
    agg128_k <<<GA, 256, 0, stream>>>(Yb, Zb, row_ptr, ssorted, hB, N);
    gemm256_k<<<GM, 256, 0, stream>>>(hB, Wt2, b2, Yb, Zb, N, 47, 64);
    aggfin_k <<<GA, 256, 0, stream>>>(Yb, Zb, row_ptr, ssorted, out, N);
}